// Round 1
// baseline (69441.162 us; speedup 1.0000x reference)
//
#include <hip/hip_runtime.h>
#include <hip/hip_bf16.h>

#define B_   16
#define C_   1024
#define Q_   128
#define S_   1152
#define D_   512
#define H_   8
#define HD_  64
#define HID_ 2048
#define L_   6
#define M_   (B_*S_)   // 18432 tokens

__device__ __forceinline__ float waveSum(float v){
  #pragma unroll
  for (int o = 32; o > 0; o >>= 1) v += __shfl_down(v, o, 64);
  return v;
}
__device__ __forceinline__ float waveMax(float v){
  #pragma unroll
  for (int o = 32; o > 0; o >>= 1) v = fmaxf(v, __shfl_down(v, o, 64));
  return v;
}

// ---------------- embedding: xy @ W_val + b_val (+ q_emb on query rows) ----------
__global__ __launch_bounds__(256) void embed_kernel(
    const float* __restrict__ x_c, const float* __restrict__ y_c,
    const float* __restrict__ x_q, const float* __restrict__ W_val,
    const float* __restrict__ b_val, const float* __restrict__ q_emb,
    float* __restrict__ X)
{
  int row = blockIdx.x;            // 0..M_-1
  int bb = row / S_, s = row % S_;
  __shared__ float xy[96];
  int tid = threadIdx.x;
  if (tid < 96) {
    float v;
    if (s < C_) {
      v = (tid < 64) ? x_c[((size_t)bb*C_ + s)*64 + tid]
                     : y_c[((size_t)bb*C_ + s)*32 + (tid - 64)];
    } else {
      v = (tid < 64) ? x_q[((size_t)bb*Q_ + (s - C_))*64 + tid] : 0.f;
    }
    xy[tid] = v;
  }
  __syncthreads();
  bool isq = (s >= C_);
  for (int n = tid; n < D_; n += 256) {
    float acc = b_val[n] + (isq ? q_emb[n] : 0.f);
    #pragma unroll 8
    for (int k = 0; k < 96; k++) acc += xy[k] * W_val[k*D_ + n];
    X[(size_t)row*D_ + n] = acc;
  }
}

// ---------------- tiled fp32 GEMM: C = act(A[M,K] @ W[N,K]^T + bias [+ Rsd]) ------
template<bool RELU, bool RES>
__global__ __launch_bounds__(256) void gemm_kernel(
    const float* __restrict__ A, const float* __restrict__ W,
    const float* __restrict__ bias, const float* __restrict__ Rsd,
    float* __restrict__ Cout, int Mm, int Nn, int Kk)
{
  __shared__ float As[16][64];
  __shared__ float Bs[16][64];
  const int bm = blockIdx.y * 64, bn = blockIdx.x * 64;
  const int tid = threadIdx.x;
  const int lr = tid >> 2;            // 0..63 row within tile
  const int lk = (tid & 3) << 2;      // 0,4,8,12
  const int tx = tid & 15, ty = tid >> 4;
  const float* Ap = A + (size_t)(bm + lr)*Kk + lk;
  const float* Wp = W + (size_t)(bn + lr)*Kk + lk;
  float acc[4][4] = {};
  for (int k0 = 0; k0 < Kk; k0 += 16) {
    float4 av = *(const float4*)(Ap + k0);
    float4 wv = *(const float4*)(Wp + k0);
    __syncthreads();
    As[lk+0][lr] = av.x; As[lk+1][lr] = av.y; As[lk+2][lr] = av.z; As[lk+3][lr] = av.w;
    Bs[lk+0][lr] = wv.x; Bs[lk+1][lr] = wv.y; Bs[lk+2][lr] = wv.z; Bs[lk+3][lr] = wv.w;
    __syncthreads();
    #pragma unroll
    for (int kk = 0; kk < 16; kk++) {
      const float4 a = *(const float4*)&As[kk][ty << 2];
      const float4 b = *(const float4*)&Bs[kk][tx << 2];
      acc[0][0] += a.x*b.x; acc[0][1] += a.x*b.y; acc[0][2] += a.x*b.z; acc[0][3] += a.x*b.w;
      acc[1][0] += a.y*b.x; acc[1][1] += a.y*b.y; acc[1][2] += a.y*b.z; acc[1][3] += a.y*b.w;
      acc[2][0] += a.z*b.x; acc[2][1] += a.z*b.y; acc[2][2] += a.z*b.z; acc[2][3] += a.z*b.w;
      acc[3][0] += a.w*b.x; acc[3][1] += a.w*b.y; acc[3][2] += a.w*b.z; acc[3][3] += a.w*b.w;
    }
  }
  const int cc = bn + (tx << 2);
  float4 bv = *(const float4*)&bias[cc];
  #pragma unroll
  for (int i = 0; i < 4; i++) {
    int r = bm + (ty << 2) + i;
    float4 o;
    o.x = acc[i][0] + bv.x; o.y = acc[i][1] + bv.y;
    o.z = acc[i][2] + bv.z; o.w = acc[i][3] + bv.w;
    if (RELU) { o.x = fmaxf(o.x, 0.f); o.y = fmaxf(o.y, 0.f); o.z = fmaxf(o.z, 0.f); o.w = fmaxf(o.w, 0.f); }
    if (RES) {
      float4 rv = *(const float4*)&Rsd[(size_t)r*Nn + cc];
      o.x += rv.x; o.y += rv.y; o.z += rv.z; o.w += rv.w;
    }
    *(float4*)&Cout[(size_t)r*Nn + cc] = o;
  }
}

// ---------------- attention: one block per (b,h,s) query row ----------------------
__global__ __launch_bounds__(256) void attn_kernel(
    const float* __restrict__ QKV, float* __restrict__ Ctx)
{
  int bid = blockIdx.x;
  int s = bid % S_;
  int h = (bid / S_) % H_;
  int bb = bid / (S_ * H_);
  const float* qrow  = QKV + (size_t)(bb*S_ + s)*(3*D_) + h*HD_;
  const float* Kbase = QKV + (size_t)(bb*S_)*(3*D_) + D_   + h*HD_;
  const float* Vbase = QKV + (size_t)(bb*S_)*(3*D_) + 2*D_ + h*HD_;
  __shared__ float q[64];
  __shared__ float p[1024];
  __shared__ float red[4];
  __shared__ float ctxa[4][64];
  int tid = threadIdx.x;
  if (tid < 64) q[tid] = qrow[tid];
  __syncthreads();

  float scores[4];
  float mymax = -1e30f;
  #pragma unroll
  for (int i = 0; i < 4; i++) {
    int k = tid + i*256;          // keys 0..1023 (masked keys >= C_ skipped entirely)
    const float* kr = Kbase + (size_t)k*(3*D_);
    float acc = 0.f;
    #pragma unroll
    for (int d = 0; d < 64; d += 4) {
      float4 kv = *(const float4*)&kr[d];
      acc += q[d]*kv.x + q[d+1]*kv.y + q[d+2]*kv.z + q[d+3]*kv.w;
    }
    scores[i] = acc * 0.125f;     // 1/sqrt(64)
    mymax = fmaxf(mymax, scores[i]);
  }
  float wm = waveMax(mymax);
  if ((tid & 63) == 0) red[tid >> 6] = wm;
  __syncthreads();
  float mx = fmaxf(fmaxf(red[0], red[1]), fmaxf(red[2], red[3]));

  float mysum = 0.f;
  #pragma unroll
  for (int i = 0; i < 4; i++) {
    float e = __expf(scores[i] - mx);
    p[tid + i*256] = e;
    mysum += e;
  }
  __syncthreads();                 // p visible; red reusable
  float ws = waveSum(mysum);
  if ((tid & 63) == 0) red[tid >> 6] = ws;
  __syncthreads();
  float denom = red[0] + red[1] + red[2] + red[3];

  int d = tid & 63, g = tid >> 6;
  float acc = 0.f;
  const float* vp = Vbase + (size_t)(g*256)*(3*D_) + d;
  #pragma unroll 4
  for (int k = 0; k < 256; k++) acc += p[g*256 + k] * vp[(size_t)k*(3*D_)];
  ctxa[g][d] = acc;
  __syncthreads();
  if (tid < 64) {
    float r = (ctxa[0][tid] + ctxa[1][tid] + ctxa[2][tid] + ctxa[3][tid]) / denom;
    Ctx[(size_t)(bb*S_ + s)*D_ + h*HD_ + tid] = r;
  }
}

// ---------------- in-place row LayerNorm over D=512 -------------------------------
__global__ __launch_bounds__(256) void ln_kernel(
    float* __restrict__ Y, const float* __restrict__ g, const float* __restrict__ b)
{
  int row = blockIdx.x, tid = threadIdx.x;
  float* yr = Y + (size_t)row*D_;
  float v0 = yr[tid], v1 = yr[tid + 256];
  __shared__ float red[4];
  float s = waveSum(v0 + v1);
  if ((tid & 63) == 0) red[tid >> 6] = s;
  __syncthreads();
  float mu = (red[0] + red[1] + red[2] + red[3]) * (1.f/512.f);
  __syncthreads();
  float d0 = v0 - mu, d1 = v1 - mu;
  float ss = waveSum(d0*d0 + d1*d1);
  if ((tid & 63) == 0) red[tid >> 6] = ss;
  __syncthreads();
  float inv = rsqrtf((red[0] + red[1] + red[2] + red[3]) * (1.f/512.f) + 1e-5f);
  yr[tid]       = d0 * inv * g[tid]       + b[tid];
  yr[tid + 256] = d1 * inv * g[tid + 256] + b[tid + 256];
}

// ---------------- head: X[:, -Q:] @ W_head[512,32] + b_head -----------------------
__global__ __launch_bounds__(64) void head_kernel(
    const float* __restrict__ X, const float* __restrict__ W_head,
    const float* __restrict__ b_head, float* __restrict__ out)
{
  int row = blockIdx.x;            // 0..B_*Q_-1
  int bb = row / Q_, qi = row % Q_;
  const float* xr = X + (size_t)(bb*S_ + C_ + qi)*D_;
  __shared__ float xs[512];
  int tid = threadIdx.x;
  for (int i = tid; i < 512; i += 64) xs[i] = xr[i];
  __syncthreads();
  if (tid < 32) {
    float acc = b_head[tid];
    #pragma unroll 8
    for (int k = 0; k < 512; k++) acc += xs[k] * W_head[k*32 + tid];
    out[(size_t)row*32 + tid] = acc;
  }
}

extern "C" void kernel_launch(void* const* d_in, const int* in_sizes, int n_in,
                              void* d_out, int out_size, void* d_ws, size_t ws_size,
                              hipStream_t stream)
{
  const float* x_c      = (const float*)d_in[0];
  const float* y_c      = (const float*)d_in[1];
  const float* x_q      = (const float*)d_in[2];
  const float* W_val    = (const float*)d_in[3];
  const float* b_val    = (const float*)d_in[4];
  const float* q_emb    = (const float*)d_in[5];
  const float* in_proj_w= (const float*)d_in[6];
  const float* in_proj_b= (const float*)d_in[7];
  const float* out_w    = (const float*)d_in[8];
  const float* out_b    = (const float*)d_in[9];
  const float* ln1_g    = (const float*)d_in[10];
  const float* ln1_b    = (const float*)d_in[11];
  const float* lin1_w   = (const float*)d_in[12];
  const float* lin1_b   = (const float*)d_in[13];
  const float* lin2_w   = (const float*)d_in[14];
  const float* lin2_b   = (const float*)d_in[15];
  const float* ln2_g    = (const float*)d_in[16];
  const float* ln2_b    = (const float*)d_in[17];
  const float* W_head   = (const float*)d_in[18];
  const float* b_head   = (const float*)d_in[19];
  float* out = (float*)d_out;

  float* bufX = (float*)d_ws;                         // [M_, D_]
  float* bufY = bufX + (size_t)M_*D_;                 // [M_, D_]
  float* ctxB = bufY + (size_t)M_*D_;                 // [M_, D_]
  float* big  = ctxB + (size_t)M_*D_;                 // [M_, 2048] (qkv [M_,1536] / hid)

  embed_kernel<<<M_, 256, 0, stream>>>(x_c, y_c, x_q, W_val, b_val, q_emb, bufX);

  for (int l = 0; l < L_; l++) {
    // QKV projection
    gemm_kernel<false,false><<<dim3((3*D_)/64, M_/64), 256, 0, stream>>>(
        bufX, in_proj_w + (size_t)l*3*D_*D_, in_proj_b + (size_t)l*3*D_,
        nullptr, big, M_, 3*D_, D_);
    // attention
    attn_kernel<<<B_*H_*S_, 256, 0, stream>>>(big, ctxB);
    // out-proj + residual -> bufY, then LN in place
    gemm_kernel<false,true><<<dim3(D_/64, M_/64), 256, 0, stream>>>(
        ctxB, out_w + (size_t)l*D_*D_, out_b + (size_t)l*D_,
        bufX, bufY, M_, D_, D_);
    ln_kernel<<<M_, 256, 0, stream>>>(bufY, ln1_g + (size_t)l*D_, ln1_b + (size_t)l*D_);
    // FFN
    gemm_kernel<true,false><<<dim3(HID_/64, M_/64), 256, 0, stream>>>(
        bufY, lin1_w + (size_t)l*HID_*D_, lin1_b + (size_t)l*HID_,
        nullptr, big, M_, HID_, D_);
    gemm_kernel<false,true><<<dim3(D_/64, M_/64), 256, 0, stream>>>(
        big, lin2_w + (size_t)l*D_*HID_, lin2_b + (size_t)l*D_,
        bufY, bufX, M_, D_, HID_);
    ln_kernel<<<M_, 256, 0, stream>>>(bufX, ln2_g + (size_t)l*D_, ln2_b + (size_t)l*D_);
  }

  head_kernel<<<B_*Q_, 64, 0, stream>>>(bufX, W_head, b_head, out);
}

// Round 2
// 21813.335 us; speedup vs baseline: 3.1834x; 3.1834x over previous
//
#include <hip/hip_runtime.h>
#include <hip/hip_bf16.h>

#define B_   16
#define C_   1024
#define Q_   128
#define S_   1152
#define D_   512
#define H_   8
#define HD_  64
#define HID_ 2048
#define L_   6
#define M_   (B_*S_)   // 18432 tokens
#define QT_  18        // S_/64 query tiles

__device__ __forceinline__ float waveSum(float v){
  #pragma unroll
  for (int o = 32; o > 0; o >>= 1) v += __shfl_down(v, o, 64);
  return v;
}

// ---------------- embedding: xy @ W_val + b_val (+ q_emb on query rows) ----------
__global__ __launch_bounds__(256) void embed_kernel(
    const float* __restrict__ x_c, const float* __restrict__ y_c,
    const float* __restrict__ x_q, const float* __restrict__ W_val,
    const float* __restrict__ b_val, const float* __restrict__ q_emb,
    float* __restrict__ X)
{
  int row = blockIdx.x;            // 0..M_-1
  int bb = row / S_, s = row % S_;
  __shared__ float xy[96];
  int tid = threadIdx.x;
  if (tid < 96) {
    float v;
    if (s < C_) {
      v = (tid < 64) ? x_c[((size_t)bb*C_ + s)*64 + tid]
                     : y_c[((size_t)bb*C_ + s)*32 + (tid - 64)];
    } else {
      v = (tid < 64) ? x_q[((size_t)bb*Q_ + (s - C_))*64 + tid] : 0.f;
    }
    xy[tid] = v;
  }
  __syncthreads();
  bool isq = (s >= C_);
  for (int n = tid; n < D_; n += 256) {
    float acc = b_val[n] + (isq ? q_emb[n] : 0.f);
    #pragma unroll 8
    for (int k = 0; k < 96; k++) acc += xy[k] * W_val[k*D_ + n];
    X[(size_t)row*D_ + n] = acc;
  }
}

// ---------------- tiled fp32 GEMM: C = act(A[M,K] @ W[N,K]^T + bias [+ Rsd]) ------
template<bool RELU, bool RES>
__global__ __launch_bounds__(256) void gemm_kernel(
    const float* __restrict__ A, const float* __restrict__ W,
    const float* __restrict__ bias, const float* __restrict__ Rsd,
    float* __restrict__ Cout, int Mm, int Nn, int Kk)
{
  __shared__ float As[16][64];
  __shared__ float Bs[16][64];
  const int bm = blockIdx.y * 64, bn = blockIdx.x * 64;
  const int tid = threadIdx.x;
  const int lr = tid >> 2;            // 0..63 row within tile
  const int lk = (tid & 3) << 2;      // 0,4,8,12
  const int tx = tid & 15, ty = tid >> 4;
  const float* Ap = A + (size_t)(bm + lr)*Kk + lk;
  const float* Wp = W + (size_t)(bn + lr)*Kk + lk;
  float acc[4][4] = {};
  for (int k0 = 0; k0 < Kk; k0 += 16) {
    float4 av = *(const float4*)(Ap + k0);
    float4 wv = *(const float4*)(Wp + k0);
    __syncthreads();
    As[lk+0][lr] = av.x; As[lk+1][lr] = av.y; As[lk+2][lr] = av.z; As[lk+3][lr] = av.w;
    Bs[lk+0][lr] = wv.x; Bs[lk+1][lr] = wv.y; Bs[lk+2][lr] = wv.z; Bs[lk+3][lr] = wv.w;
    __syncthreads();
    #pragma unroll
    for (int kk = 0; kk < 16; kk++) {
      const float4 a = *(const float4*)&As[kk][ty << 2];
      const float4 b = *(const float4*)&Bs[kk][tx << 2];
      acc[0][0] += a.x*b.x; acc[0][1] += a.x*b.y; acc[0][2] += a.x*b.z; acc[0][3] += a.x*b.w;
      acc[1][0] += a.y*b.x; acc[1][1] += a.y*b.y; acc[1][2] += a.y*b.z; acc[1][3] += a.y*b.w;
      acc[2][0] += a.z*b.x; acc[2][1] += a.z*b.y; acc[2][2] += a.z*b.z; acc[2][3] += a.z*b.w;
      acc[3][0] += a.w*b.x; acc[3][1] += a.w*b.y; acc[3][2] += a.w*b.z; acc[3][3] += a.w*b.w;
    }
  }
  const int cc = bn + (tx << 2);
  float4 bv = *(const float4*)&bias[cc];
  #pragma unroll
  for (int i = 0; i < 4; i++) {
    int r = bm + (ty << 2) + i;
    float4 o;
    o.x = acc[i][0] + bv.x; o.y = acc[i][1] + bv.y;
    o.z = acc[i][2] + bv.z; o.w = acc[i][3] + bv.w;
    if (RELU) { o.x = fmaxf(o.x, 0.f); o.y = fmaxf(o.y, 0.f); o.z = fmaxf(o.z, 0.f); o.w = fmaxf(o.w, 0.f); }
    if (RES) {
      float4 rv = *(const float4*)&Rsd[(size_t)r*Nn + cc];
      o.x += rv.x; o.y += rv.y; o.z += rv.z; o.w += rv.w;
    }
    *(float4*)&Cout[(size_t)r*Nn + cc] = o;
  }
}

// ---------------- flash attention: one block per (b,h, 64-query tile) -------------
// thread (r,g): q-row r (0..63), key group g (0..3; keys g*16..g*16+15 per tile)
// ctx[64] partial accumulator per thread, reduced across g-lanes at the end.
__global__ __launch_bounds__(256) void fattn_kernel(
    const float* __restrict__ QKV, float* __restrict__ Ctx)
{
  __shared__ float Qs[64][65];
  __shared__ float Ks[64][65];
  __shared__ float Vs[64][65];
  const int bid = blockIdx.x;
  const int qt = bid % QT_;
  const int h  = (bid / QT_) % H_;
  const int bb = bid / (QT_ * H_);
  const int tid = threadIdx.x;
  const int r = tid >> 2;            // q-row within tile
  const int g = tid & 3;             // key group

  const float* Qbase = QKV + ((size_t)(bb*S_) + qt*64)*(3*D_) + h*HD_;
  const float* Kbase = QKV + (size_t)(bb*S_)*(3*D_) + D_   + h*HD_;
  const float* Vbase = Kbase + D_;

  // load Q tile (coalesced: 16 threads cover one 256B row segment)
  for (int i = tid; i < 1024; i += 256) {
    int row = i >> 4, d4 = (i & 15) << 2;
    *(float4*)&Qs[row][d4] = *(const float4*)&Qbase[(size_t)row*(3*D_) + d4];
  }

  float m = -1e30f, l = 0.f;
  float ctx[64];
  #pragma unroll
  for (int d = 0; d < 64; d++) ctx[d] = 0.f;

  for (int kt = 0; kt < C_/64; kt++) {           // only unmasked keys 0..1023
    __syncthreads();
    for (int i = tid; i < 1024; i += 256) {
      int row = i >> 4, d4 = (i & 15) << 2;
      size_t goff = ((size_t)kt*64 + row)*(3*D_) + d4;
      *(float4*)&Ks[row][d4] = *(const float4*)&Kbase[goff];
      *(float4*)&Vs[row][d4] = *(const float4*)&Vbase[goff];
    }
    __syncthreads();

    // scores: 16 keys per thread
    float s[16];
    #pragma unroll
    for (int j = 0; j < 16; j++) s[j] = 0.f;
    #pragma unroll
    for (int d = 0; d < 64; d += 4) {
      const float4 qv = *(const float4*)&Qs[r][d];
      #pragma unroll
      for (int j = 0; j < 16; j++) {
        const float4 kv = *(const float4*)&Ks[g*16 + j][d];
        s[j] += qv.x*kv.x + qv.y*kv.y + qv.z*kv.z + qv.w*kv.w;
      }
    }
    float tmax = -1e30f;
    #pragma unroll
    for (int j = 0; j < 16; j++) { s[j] *= 0.125f; tmax = fmaxf(tmax, s[j]); }
    tmax = fmaxf(tmax, __shfl_xor(tmax, 1, 64));
    tmax = fmaxf(tmax, __shfl_xor(tmax, 2, 64));
    const float mn = fmaxf(m, tmax);
    const float scale = __expf(m - mn);
    float psum = 0.f;
    #pragma unroll
    for (int j = 0; j < 16; j++) { s[j] = __expf(s[j] - mn); psum += s[j]; }
    psum += __shfl_xor(psum, 1, 64);
    psum += __shfl_xor(psum, 2, 64);
    l = l * scale + psum;
    m = mn;
    #pragma unroll
    for (int d = 0; d < 64; d++) ctx[d] *= scale;

    // PV: accumulate 16 keys into 64-wide partial ctx
    #pragma unroll
    for (int j = 0; j < 16; j++) {
      const float p = s[j];
      #pragma unroll
      for (int d = 0; d < 64; d += 4) {
        const float4 vv = *(const float4*)&Vs[g*16 + j][d];
        ctx[d]   += p*vv.x; ctx[d+1] += p*vv.y;
        ctx[d+2] += p*vv.z; ctx[d+3] += p*vv.w;
      }
    }
  }

  // reduce partials across the 4 g-lanes (adjacent lanes), then write segment
  #pragma unroll
  for (int d = 0; d < 64; d++) {
    ctx[d] += __shfl_xor(ctx[d], 1, 64);
    ctx[d] += __shfl_xor(ctx[d], 2, 64);
  }
  const float invl = 1.f / l;
  float* op = Ctx + ((size_t)(bb*S_) + qt*64 + r)*D_ + h*HD_;
  #pragma unroll
  for (int j = 0; j < 16; j += 4) {
    int d = g*16 + j;
    float4 o = { ctx[d]*invl, ctx[d+1]*invl, ctx[d+2]*invl, ctx[d+3]*invl };
    *(float4*)&op[d] = o;
  }
}

// ---------------- in-place row LayerNorm over D=512 -------------------------------
__global__ __launch_bounds__(256) void ln_kernel(
    float* __restrict__ Y, const float* __restrict__ g, const float* __restrict__ b)
{
  int row = blockIdx.x, tid = threadIdx.x;
  float* yr = Y + (size_t)row*D_;
  float v0 = yr[tid], v1 = yr[tid + 256];
  __shared__ float red[4];
  float s = waveSum(v0 + v1);
  if ((tid & 63) == 0) red[tid >> 6] = s;
  __syncthreads();
  float mu = (red[0] + red[1] + red[2] + red[3]) * (1.f/512.f);
  __syncthreads();
  float d0 = v0 - mu, d1 = v1 - mu;
  float ss = waveSum(d0*d0 + d1*d1);
  if ((tid & 63) == 0) red[tid >> 6] = ss;
  __syncthreads();
  float inv = rsqrtf((red[0] + red[1] + red[2] + red[3]) * (1.f/512.f) + 1e-5f);
  yr[tid]       = d0 * inv * g[tid]       + b[tid];
  yr[tid + 256] = d1 * inv * g[tid + 256] + b[tid + 256];
}

// ---------------- head: X[:, -Q:] @ W_head[512,32] + b_head -----------------------
__global__ __launch_bounds__(64) void head_kernel(
    const float* __restrict__ X, const float* __restrict__ W_head,
    const float* __restrict__ b_head, float* __restrict__ out)
{
  int row = blockIdx.x;            // 0..B_*Q_-1
  int bb = row / Q_, qi = row % Q_;
  const float* xr = X + (size_t)(bb*S_ + C_ + qi)*D_;
  __shared__ float xs[512];
  int tid = threadIdx.x;
  for (int i = tid; i < 512; i += 64) xs[i] = xr[i];
  __syncthreads();
  if (tid < 32) {
    float acc = b_head[tid];
    #pragma unroll 8
    for (int k = 0; k < 512; k++) acc += xs[k] * W_head[k*32 + tid];
    out[(size_t)row*32 + tid] = acc;
  }
}

extern "C" void kernel_launch(void* const* d_in, const int* in_sizes, int n_in,
                              void* d_out, int out_size, void* d_ws, size_t ws_size,
                              hipStream_t stream)
{
  const float* x_c      = (const float*)d_in[0];
  const float* y_c      = (const float*)d_in[1];
  const float* x_q      = (const float*)d_in[2];
  const float* W_val    = (const float*)d_in[3];
  const float* b_val    = (const float*)d_in[4];
  const float* q_emb    = (const float*)d_in[5];
  const float* in_proj_w= (const float*)d_in[6];
  const float* in_proj_b= (const float*)d_in[7];
  const float* out_w    = (const float*)d_in[8];
  const float* out_b    = (const float*)d_in[9];
  const float* ln1_g    = (const float*)d_in[10];
  const float* ln1_b    = (const float*)d_in[11];
  const float* lin1_w   = (const float*)d_in[12];
  const float* lin1_b   = (const float*)d_in[13];
  const float* lin2_w   = (const float*)d_in[14];
  const float* lin2_b   = (const float*)d_in[15];
  const float* ln2_g    = (const float*)d_in[16];
  const float* ln2_b    = (const float*)d_in[17];
  const float* W_head   = (const float*)d_in[18];
  const float* b_head   = (const float*)d_in[19];
  float* out = (float*)d_out;

  float* bufX = (float*)d_ws;                         // [M_, D_]
  float* bufY = bufX + (size_t)M_*D_;                 // [M_, D_]
  float* ctxB = bufY + (size_t)M_*D_;                 // [M_, D_]
  float* big  = ctxB + (size_t)M_*D_;                 // [M_, 2048] (qkv [M_,1536] / hid)

  embed_kernel<<<M_, 256, 0, stream>>>(x_c, y_c, x_q, W_val, b_val, q_emb, bufX);

  for (int l = 0; l < L_; l++) {
    // QKV projection
    gemm_kernel<false,false><<<dim3((3*D_)/64, M_/64), 256, 0, stream>>>(
        bufX, in_proj_w + (size_t)l*3*D_*D_, in_proj_b + (size_t)l*3*D_,
        nullptr, big, M_, 3*D_, D_);
    // flash attention
    fattn_kernel<<<B_*H_*QT_, 256, 0, stream>>>(big, ctxB);
    // out-proj + residual -> bufY, then LN in place
    gemm_kernel<false,true><<<dim3(D_/64, M_/64), 256, 0, stream>>>(
        ctxB, out_w + (size_t)l*D_*D_, out_b + (size_t)l*D_,
        bufX, bufY, M_, D_, D_);
    ln_kernel<<<M_, 256, 0, stream>>>(bufY, ln1_g + (size_t)l*D_, ln1_b + (size_t)l*D_);
    // FFN
    gemm_kernel<true,false><<<dim3(HID_/64, M_/64), 256, 0, stream>>>(
        bufY, lin1_w + (size_t)l*HID_*D_, lin1_b + (size_t)l*HID_,
        nullptr, big, M_, HID_, D_);
    gemm_kernel<false,true><<<dim3(D_/64, M_/64), 256, 0, stream>>>(
        big, lin2_w + (size_t)l*D_*HID_, lin2_b + (size_t)l*D_,
        bufY, bufX, M_, D_, HID_);
    ln_kernel<<<M_, 256, 0, stream>>>(bufX, ln2_g + (size_t)l*D_, ln2_b + (size_t)l*D_);
  }

  head_kernel<<<B_*Q_, 64, 0, stream>>>(bufX, W_head, b_head, out);
}

// Round 3
// 2615.675 us; speedup vs baseline: 26.5481x; 8.3395x over previous
//
#include <hip/hip_runtime.h>

#define B_   16
#define C_   1024
#define Q_   128
#define S_   1152
#define D_   512
#define H_   8
#define HID_ 2048
#define L_   6
#define M_   (B_*S_)   // 18432 tokens
#define QT_  18        // S_/64 query tiles

typedef short bf16x8 __attribute__((ext_vector_type(8)));
typedef float f32x4  __attribute__((ext_vector_type(4)));
#define MFMA16(a,b,c) __builtin_amdgcn_mfma_f32_16x16x32_bf16(a,b,c,0,0,0)

__device__ __forceinline__ unsigned short f2b(float f){
  union { float f; unsigned u; } v; v.f = f;
  return (unsigned short)((v.u + 0x7FFF + ((v.u >> 16) & 1)) >> 16);  // RNE
}
__device__ __forceinline__ void gload16(const void* g, void* l){
  __builtin_amdgcn_global_load_lds((const __attribute__((address_space(1))) void*)g,
                                   (__attribute__((address_space(3))) void*)l, 16, 0, 0);
}
__device__ __forceinline__ float waveSum(float v){
  #pragma unroll
  for (int o = 32; o > 0; o >>= 1) v += __shfl_down(v, o, 64);
  return v;
}

// ---------------- fp32 -> bf16 weight conversion ----------------------------------
__global__ __launch_bounds__(256) void f2b_kernel(
    const float* __restrict__ in, unsigned short* __restrict__ out, int n4)
{
  int i = blockIdx.x*256 + threadIdx.x;
  for (; i < n4; i += gridDim.x*256) {
    float4 v = ((const float4*)in)[i];
    ushort4 o = { f2b(v.x), f2b(v.y), f2b(v.z), f2b(v.w) };
    ((ushort4*)out)[i] = o;
  }
}

// ---------------- embedding: xy @ W_val + b_val (+ q_emb), dual fp32/bf16 out -----
__global__ __launch_bounds__(256) void embed_kernel(
    const float* __restrict__ x_c, const float* __restrict__ y_c,
    const float* __restrict__ x_q, const float* __restrict__ W_val,
    const float* __restrict__ b_val, const float* __restrict__ q_emb,
    float* __restrict__ X, unsigned short* __restrict__ Xb)
{
  int row = blockIdx.x;            // 0..M_-1
  int bb = row / S_, s = row % S_;
  __shared__ float xy[96];
  int tid = threadIdx.x;
  if (tid < 96) {
    float v;
    if (s < C_) {
      v = (tid < 64) ? x_c[((size_t)bb*C_ + s)*64 + tid]
                     : y_c[((size_t)bb*C_ + s)*32 + (tid - 64)];
    } else {
      v = (tid < 64) ? x_q[((size_t)bb*Q_ + (s - C_))*64 + tid] : 0.f;
    }
    xy[tid] = v;
  }
  __syncthreads();
  bool isq = (s >= C_);
  for (int n = tid; n < D_; n += 256) {
    float acc = b_val[n] + (isq ? q_emb[n] : 0.f);
    #pragma unroll 8
    for (int k = 0; k < 96; k++) acc += xy[k] * W_val[k*D_ + n];
    X [(size_t)row*D_ + n] = acc;
    Xb[(size_t)row*D_ + n] = f2b(acc);
  }
}

// ---------------- bf16 MFMA GEMM: C = act(A[M,K] @ W[N,K]^T + bias [+ Rsd]) -------
// 128x128 tile, BK=32, 4 waves (2x2), each wave 64x64 via 4x4 16x16x32 frags.
template<int RELU, int RES, int BOUT>
__global__ __launch_bounds__(256) void bgemm_kernel(
    const unsigned short* __restrict__ A, const unsigned short* __restrict__ W,
    const float* __restrict__ bias, const float* __restrict__ Rsd,
    float* __restrict__ Cf, unsigned short* __restrict__ Cb, int Nn, int Kk)
{
  __shared__ short As[4096];     // [128][32] bf16
  __shared__ short Bs[4096];
  const int bm = blockIdx.y * 128, bn = blockIdx.x * 128;
  const int tid = threadIdx.x;
  const int w = tid >> 6, lane = tid & 63, l15 = lane & 15, l4 = lane >> 4;
  const int wm = w >> 1, wn = w & 1;
  f32x4 acc[4][4] = {};
  const size_t strA = (size_t)Kk * 2;          // bytes per row
  const char* Abase = (const char*)(A + (size_t)bm * Kk);
  const char* Wbase = (const char*)(W + (size_t)bn * Kk);
  const size_t soff = (size_t)(tid >> 2) * strA + (size_t)((tid & 3) * 16);
  char* lA = (char*)As + w * 1024;             // wave-uniform LDS base (+lane*16 by HW)
  char* lB = (char*)Bs + w * 1024;

  for (int k0 = 0; k0 < Kk; k0 += 32) {
    __syncthreads();
    const char* a0 = Abase + soff + k0*2;
    const char* b0 = Wbase + soff + k0*2;
    gload16(a0,             lA);
    gload16(a0 + 64*strA,   lA + 4096);
    gload16(b0,             lB);
    gload16(b0 + 64*strA,   lB + 4096);
    __syncthreads();
    bf16x8 af[4], bfr[4];
    #pragma unroll
    for (int mf = 0; mf < 4; mf++)
      af[mf] = *(const bf16x8*)(As + (wm*64 + mf*16 + l15)*32 + l4*8);
    #pragma unroll
    for (int nf = 0; nf < 4; nf++)
      bfr[nf] = *(const bf16x8*)(Bs + (wn*64 + nf*16 + l15)*32 + l4*8);
    #pragma unroll
    for (int mf = 0; mf < 4; mf++)
      #pragma unroll
      for (int nf = 0; nf < 4; nf++)
        acc[mf][nf] = MFMA16(af[mf], bfr[nf], acc[mf][nf]);
  }

  #pragma unroll
  for (int mf = 0; mf < 4; mf++) {
    #pragma unroll
    for (int nf = 0; nf < 4; nf++) {
      const int ccol = bn + wn*64 + nf*16 + l15;
      const float bv = bias[ccol];
      #pragma unroll
      for (int r = 0; r < 4; r++) {
        const int rrow = bm + wm*64 + mf*16 + l4*4 + r;
        float o = acc[mf][nf][r] + bv;
        if (RELU) o = fmaxf(o, 0.f);
        if (RES)  o += Rsd[(size_t)rrow*Nn + ccol];
        if (BOUT) Cb[(size_t)rrow*Nn + ccol] = f2b(o);
        else      Cf[(size_t)rrow*Nn + ccol] = o;
      }
    }
  }
}

// ---------------- MFMA flash attention ---------------------------------------------
// block = (b,h, 64-q-tile); 4 waves x 16 q-rows. K-tiles of 64 over keys 0..1023.
// LDS rows padded to 144B (16B-aligned, stride 9 granules => conflict-free b128).
__global__ __launch_bounds__(256) void mattn_kernel(
    const unsigned short* __restrict__ QKV, unsigned short* __restrict__ Ctx)
{
  __shared__ short Ks[64*72];      // [key][hd], 144B row stride
  __shared__ short Vt[64*72];      // [hd][key] transposed, slot-XOR swizzled
  __shared__ short Ps[4*16*72];    // per-wave P tile [q][key]
  const int bid = blockIdx.x;
  const int qt = bid % QT_;
  const int h  = (bid / QT_) % H_;
  const int bb = bid / (QT_*H_);
  const int tid = threadIdx.x;
  const int w = tid >> 6, lane = tid & 63, l15 = lane & 15, l4 = lane >> 4;

  const size_t rowQ = (size_t)bb*S_ + (size_t)qt*64 + w*16 + l15;
  const unsigned short* qp = QKV + rowQ*1536 + h*64;
  const bf16x8 qf0 = *(const bf16x8*)(qp + l4*8);
  const bf16x8 qf1 = *(const bf16x8*)(qp + 32 + l4*8);

  const unsigned short* Kg = QKV + (size_t)bb*S_*1536 + 512 + h*64;
  const unsigned short* Vg = Kg + 512;

  f32x4 ctx[4] = {};
  float m_r[4], l_r[4];
  #pragma unroll
  for (int r = 0; r < 4; r++) { m_r[r] = -3.0e38f; l_r[r] = 0.f; }

  char* PsW = (char*)Ps + w*2304;            // 16*144 bytes per wave

  const int skey = tid >> 3, shc = tid & 7;  // K staging: key row, 16B hd-chunk
  const int vp   = tid >> 3, vhc = tid & 7;  // V staging: key pair, 16B hd-chunk

  for (int kt = 0; kt < 16; kt++) {
    __syncthreads();
    { // stage K tile [64][64] bf16 (2 rounds of 32 keys)
      const unsigned short* g0 = Kg + (size_t)(kt*64 + skey)*1536 + shc*8;
      bf16x8 k0v = *(const bf16x8*)g0;
      bf16x8 k1v = *(const bf16x8*)(g0 + 32*1536);
      *(bf16x8*)((char*)Ks + skey*144      + shc*16) = k0v;
      *(bf16x8*)((char*)Ks + (skey+32)*144 + shc*16) = k1v;
    }
    { // stage V transposed: Vt[hd][key], element key k at slot ((k>>3)^hc)
      const unsigned short* g0 = Vg + (size_t)(kt*64 + 2*vp)*1536 + vhc*8;
      bf16x8 c0 = *(const bf16x8*)g0;
      bf16x8 c1 = *(const bf16x8*)(g0 + 1536);
      #pragma unroll
      for (int j = 0; j < 8; j++) {
        const int hd = vhc*8 + j;
        unsigned int val = (unsigned int)(unsigned short)c0[j]
                         | ((unsigned int)(unsigned short)c1[j] << 16);
        *(unsigned int*)((char*)Vt + hd*144 + ((4*vp) ^ (vhc<<4))) = val;
      }
    }
    __syncthreads();

    // S = Q K^T  (scores for 16 q-rows x 64 keys per wave)
    f32x4 sac[4] = {};
    #pragma unroll
    for (int nf = 0; nf < 4; nf++) {
      const char* kb = (char*)Ks + (nf*16 + l15)*144 + l4*16;
      bf16x8 b0 = *(const bf16x8*)kb;
      bf16x8 b1 = *(const bf16x8*)(kb + 64);
      sac[nf] = MFMA16(qf0, b0, sac[nf]);
      sac[nf] = MFMA16(qf1, b1, sac[nf]);
    }

    // online softmax (per reg r -> q-row l4*4+r), write P bf16 to LDS
    float scl[4];
    #pragma unroll
    for (int r = 0; r < 4; r++) {
      float s0 = sac[0][r]*0.125f, s1 = sac[1][r]*0.125f,
            s2 = sac[2][r]*0.125f, s3 = sac[3][r]*0.125f;
      float t = fmaxf(fmaxf(s0,s1), fmaxf(s2,s3));
      t = fmaxf(t, __shfl_xor(t, 1, 64));
      t = fmaxf(t, __shfl_xor(t, 2, 64));
      t = fmaxf(t, __shfl_xor(t, 4, 64));
      t = fmaxf(t, __shfl_xor(t, 8, 64));
      const float mn = fmaxf(m_r[r], t);
      scl[r] = __expf(m_r[r] - mn);
      m_r[r] = mn;
      float p0 = __expf(s0 - mn), p1 = __expf(s1 - mn),
            p2 = __expf(s2 - mn), p3 = __expf(s3 - mn);
      float ps = p0 + p1 + p2 + p3;
      ps += __shfl_xor(ps, 1, 64);
      ps += __shfl_xor(ps, 2, 64);
      ps += __shfl_xor(ps, 4, 64);
      ps += __shfl_xor(ps, 8, 64);
      l_r[r] = l_r[r]*scl[r] + ps;
      unsigned short* pw = (unsigned short*)(PsW + (l4*4 + r)*144);
      pw[ 0 + l15] = f2b(p0);
      pw[16 + l15] = f2b(p1);
      pw[32 + l15] = f2b(p2);
      pw[48 + l15] = f2b(p3);
      ctx[0][r] *= scl[r]; ctx[1][r] *= scl[r];
      ctx[2][r] *= scl[r]; ctx[3][r] *= scl[r];
    }

    // PV: ctx += P(16xkeys) * V(keys x 64hd)
    const char* pb = PsW + l15*144 + l4*16;
    const bf16x8 pf0 = *(const bf16x8*)pb;
    const bf16x8 pf1 = *(const bf16x8*)(pb + 64);
    #pragma unroll
    for (int hf = 0; hf < 4; hf++) {
      const int hd = hf*16 + l15;
      const int hc = (hd >> 3) & 7;
      const char* vb = (char*)Vt + hd*144;
      bf16x8 v0 = *(const bf16x8*)(vb + ((l4*16)     ^ (hc<<4)));
      bf16x8 v1 = *(const bf16x8*)(vb + (((l4+4)*16) ^ (hc<<4)));
      ctx[hf] = MFMA16(pf0, v0, ctx[hf]);
      ctx[hf] = MFMA16(pf1, v1, ctx[hf]);
    }
  }

  // epilogue: divide by l, store bf16 ctx
  #pragma unroll
  for (int r = 0; r < 4; r++) {
    const float invl = 1.0f / l_r[r];
    const size_t row = (size_t)bb*S_ + (size_t)qt*64 + w*16 + l4*4 + r;
    unsigned short* op = Ctx + row*512 + h*64;
    op[ 0 + l15] = f2b(ctx[0][r]*invl);
    op[16 + l15] = f2b(ctx[1][r]*invl);
    op[32 + l15] = f2b(ctx[2][r]*invl);
    op[48 + l15] = f2b(ctx[3][r]*invl);
  }
}

// ---------------- row LayerNorm over D=512, dual fp32/bf16 out ---------------------
__global__ __launch_bounds__(256) void ln_kernel(
    const float* __restrict__ Yin, const float* __restrict__ g, const float* __restrict__ b,
    float* __restrict__ Xf, unsigned short* __restrict__ Xb)
{
  int row = blockIdx.x, tid = threadIdx.x;
  const float* yr = Yin + (size_t)row*D_;
  float v0 = yr[tid], v1 = yr[tid + 256];
  __shared__ float red[4];
  float s = waveSum(v0 + v1);
  if ((tid & 63) == 0) red[tid >> 6] = s;
  __syncthreads();
  float mu = (red[0] + red[1] + red[2] + red[3]) * (1.f/512.f);
  __syncthreads();
  float d0 = v0 - mu, d1 = v1 - mu;
  float ss = waveSum(d0*d0 + d1*d1);
  if ((tid & 63) == 0) red[tid >> 6] = ss;
  __syncthreads();
  float inv = rsqrtf((red[0] + red[1] + red[2] + red[3]) * (1.f/512.f) + 1e-5f);
  float o0 = d0 * inv * g[tid]       + b[tid];
  float o1 = d1 * inv * g[tid + 256] + b[tid + 256];
  Xf[(size_t)row*D_ + tid]       = o0;
  Xf[(size_t)row*D_ + tid + 256] = o1;
  Xb[(size_t)row*D_ + tid]       = f2b(o0);
  Xb[(size_t)row*D_ + tid + 256] = f2b(o1);
}

// ---------------- head: X[:, -Q:] @ W_head[512,32] + b_head ------------------------
__global__ __launch_bounds__(64) void head_kernel(
    const float* __restrict__ X, const float* __restrict__ W_head,
    const float* __restrict__ b_head, float* __restrict__ out)
{
  int row = blockIdx.x;            // 0..B_*Q_-1
  int bb = row / Q_, qi = row % Q_;
  const float* xr = X + (size_t)(bb*S_ + C_ + qi)*D_;
  __shared__ float xs[512];
  int tid = threadIdx.x;
  for (int i = tid; i < 512; i += 64) xs[i] = xr[i];
  __syncthreads();
  if (tid < 32) {
    float acc = b_head[tid];
    #pragma unroll 8
    for (int k = 0; k < 512; k++) acc += xs[k] * W_head[k*32 + tid];
    out[(size_t)row*32 + tid] = acc;
  }
}

extern "C" void kernel_launch(void* const* d_in, const int* in_sizes, int n_in,
                              void* d_out, int out_size, void* d_ws, size_t ws_size,
                              hipStream_t stream)
{
  const float* x_c      = (const float*)d_in[0];
  const float* y_c      = (const float*)d_in[1];
  const float* x_q      = (const float*)d_in[2];
  const float* W_val    = (const float*)d_in[3];
  const float* b_val    = (const float*)d_in[4];
  const float* q_emb    = (const float*)d_in[5];
  const float* in_proj_w= (const float*)d_in[6];
  const float* in_proj_b= (const float*)d_in[7];
  const float* out_w    = (const float*)d_in[8];
  const float* out_b    = (const float*)d_in[9];
  const float* ln1_g    = (const float*)d_in[10];
  const float* ln1_b    = (const float*)d_in[11];
  const float* lin1_w   = (const float*)d_in[12];
  const float* lin1_b   = (const float*)d_in[13];
  const float* lin2_w   = (const float*)d_in[14];
  const float* lin2_b   = (const float*)d_in[15];
  const float* ln2_g    = (const float*)d_in[16];
  const float* ln2_b    = (const float*)d_in[17];
  const float* W_head   = (const float*)d_in[18];
  const float* b_head   = (const float*)d_in[19];
  float* out = (float*)d_out;

  // workspace layout (~245 MB)
  char* p = (char*)d_ws;
  float* X = (float*)p;                 p += (size_t)M_*D_*4;       // fp32 residual stream
  char*  YH = p;                        p += (size_t)M_*HID_*2;     // Y fp32 (outproj) / hid bf16 (alias)
  float* Y = (float*)YH;
  unsigned short* hid = (unsigned short*)YH;
  unsigned short* Xb   = (unsigned short*)p; p += (size_t)M_*D_*2;
  unsigned short* qkv  = (unsigned short*)p; p += (size_t)M_*3*D_*2;
  unsigned short* ctxb = (unsigned short*)p; p += (size_t)M_*D_*2;
  unsigned short* ipwB = (unsigned short*)p; p += (size_t)L_*3*D_*D_*2;
  unsigned short* owB  = (unsigned short*)p; p += (size_t)L_*D_*D_*2;
  unsigned short* w1B  = (unsigned short*)p; p += (size_t)L_*HID_*D_*2;
  unsigned short* w2B  = (unsigned short*)p; p += (size_t)L_*D_*HID_*2;

  // convert weights to bf16
  f2b_kernel<<<512, 256, 0, stream>>>(in_proj_w, ipwB, L_*3*D_*D_/4);
  f2b_kernel<<<512, 256, 0, stream>>>(out_w,     owB,  L_*D_*D_/4);
  f2b_kernel<<<512, 256, 0, stream>>>(lin1_w,    w1B,  L_*HID_*D_/4);
  f2b_kernel<<<512, 256, 0, stream>>>(lin2_w,    w2B,  L_*D_*HID_/4);

  embed_kernel<<<M_, 256, 0, stream>>>(x_c, y_c, x_q, W_val, b_val, q_emb, X, Xb);

  for (int l = 0; l < L_; l++) {
    // QKV projection (bf16 out)
    bgemm_kernel<0,0,1><<<dim3(12, 144), 256, 0, stream>>>(
        Xb, ipwB + (size_t)l*3*D_*D_, in_proj_b + (size_t)l*3*D_,
        nullptr, nullptr, qkv, 3*D_, D_);
    // attention
    mattn_kernel<<<B_*H_*QT_, 256, 0, stream>>>(qkv, ctxb);
    // out-proj + residual(X) -> Y fp32
    bgemm_kernel<0,1,0><<<dim3(4, 144), 256, 0, stream>>>(
        ctxb, owB + (size_t)l*D_*D_, out_b + (size_t)l*D_,
        X, Y, nullptr, D_, D_);
    ln_kernel<<<M_, 256, 0, stream>>>(Y, ln1_g + (size_t)l*D_, ln1_b + (size_t)l*D_, X, Xb);
    // FFN1 (relu, bf16 out)
    bgemm_kernel<1,0,1><<<dim3(16, 144), 256, 0, stream>>>(
        Xb, w1B + (size_t)l*HID_*D_, lin1_b + (size_t)l*HID_,
        nullptr, nullptr, hid, HID_, D_);
    // FFN2 + residual(X) -> X (in-place)
    bgemm_kernel<0,1,0><<<dim3(4, 144), 256, 0, stream>>>(
        hid, w2B + (size_t)l*D_*HID_, lin2_b + (size_t)l*D_,
        X, X, nullptr, D_, HID_);
    ln_kernel<<<M_, 256, 0, stream>>>(X, ln2_g + (size_t)l*D_, ln2_b + (size_t)l*D_, X, Xb);
  }

  head_kernel<<<B_*Q_, 64, 0, stream>>>(X, W_head, b_head, out);
}

// Round 4
// 2116.814 us; speedup vs baseline: 32.8046x; 1.2357x over previous
//
#include <hip/hip_runtime.h>

#define B_   16
#define C_   1024
#define Q_   128
#define S_   1152
#define D_   512
#define H_   8
#define HID_ 2048
#define L_   6
#define M_   (B_*S_)   // 18432 tokens
#define QT_  18        // S_/64 query tiles

typedef short bf16x8 __attribute__((ext_vector_type(8)));
typedef float f32x4  __attribute__((ext_vector_type(4)));
#define MFMA16(a,b,c) __builtin_amdgcn_mfma_f32_16x16x32_bf16(a,b,c,0,0,0)

__device__ __forceinline__ unsigned short f2b(float f){
  union { float f; unsigned u; } v; v.f = f;
  return (unsigned short)((v.u + 0x7FFF + ((v.u >> 16) & 1)) >> 16);  // RNE
}
__device__ __forceinline__ void gload16(const void* g, void* l){
  __builtin_amdgcn_global_load_lds((const __attribute__((address_space(1))) void*)g,
                                   (__attribute__((address_space(3))) void*)l, 16, 0, 0);
}
__device__ __forceinline__ float waveSum(float v){
  #pragma unroll
  for (int o = 32; o > 0; o >>= 1) v += __shfl_down(v, o, 64);
  return v;
}

// ---------------- fp32 -> bf16 weight conversion ----------------------------------
__global__ __launch_bounds__(256) void f2b_kernel(
    const float* __restrict__ in, unsigned short* __restrict__ out, int n4)
{
  int i = blockIdx.x*256 + threadIdx.x;
  for (; i < n4; i += gridDim.x*256) {
    float4 v = ((const float4*)in)[i];
    ushort4 o = { f2b(v.x), f2b(v.y), f2b(v.z), f2b(v.w) };
    ((ushort4*)out)[i] = o;
  }
}

// ---------------- pack XY [M,128] bf16: x | y/0 | 1 | isq | zeros ------------------
__global__ __launch_bounds__(256) void packxy_kernel(
    const float* __restrict__ x_c, const float* __restrict__ y_c,
    const float* __restrict__ x_q, unsigned short* __restrict__ XY)
{
  int idx = blockIdx.x*256 + threadIdx.x;
  const int n = M_*128;
  for (; idx < n; idx += gridDim.x*256) {
    int row = idx >> 7, col = idx & 127;
    int bb = row / S_, s = row % S_;
    float v;
    if (col < 64) {
      v = (s < C_) ? x_c[((size_t)bb*C_ + s)*64 + col]
                   : x_q[((size_t)bb*Q_ + (s - C_))*64 + col];
    } else if (col < 96) {
      v = (s < C_) ? y_c[((size_t)bb*C_ + s)*32 + (col - 64)] : 0.f;
    } else if (col == 96) {
      v = 1.f;
    } else if (col == 97) {
      v = (s >= C_) ? 1.f : 0.f;
    } else v = 0.f;
    XY[idx] = f2b(v);
  }
}

// ---------------- build Wemb [512][128] bf16 (W_val^T | b_val | q_emb | 0) ---------
__global__ __launch_bounds__(256) void wemb_kernel(
    const float* __restrict__ W_val, const float* __restrict__ b_val,
    const float* __restrict__ q_emb, unsigned short* __restrict__ Wemb)
{
  int idx = blockIdx.x*256 + threadIdx.x;   // 512*128 = 65536 = 256*256
  int nn = idx >> 7, k = idx & 127;
  float v;
  if (k < 96)       v = W_val[k*D_ + nn];
  else if (k == 96) v = b_val[nn];
  else if (k == 97) v = q_emb[nn];
  else              v = 0.f;
  Wemb[idx] = f2b(v);
}

// ---------------- bf16 MFMA GEMM, 2-phase double-buffered --------------------------
// C = act(A[M,K] @ W[N,K]^T + bias [+ Rsd]); 128x128 tile, BK=32, 4 waves (2x2).
// BOUT: 0 = f32 out, 1 = bf16 out, 2 = both.
template<int RELU, int RES, int BOUT>
__global__ __launch_bounds__(256) void bgemm_kernel(
    const unsigned short* __restrict__ A, const unsigned short* __restrict__ W,
    const float* __restrict__ bias, const float* __restrict__ Rsd,
    float* __restrict__ Cf, unsigned short* __restrict__ Cb, int Nn, int Kk)
{
  __shared__ short As[2][4096];     // [buf][128][32] bf16
  __shared__ short Bs[2][4096];
  // XCD-bijective swizzle (all grids have nwg % 8 == 0)
  int lin = blockIdx.y * gridDim.x + blockIdx.x;
  const int nwg = gridDim.x * gridDim.y;
  const int cpx = nwg >> 3;
  lin = (lin & 7) * cpx + (lin >> 3);
  const int bm = (lin / gridDim.x) * 128, bn = (lin % gridDim.x) * 128;

  const int tid = threadIdx.x;
  const int w = tid >> 6, lane = tid & 63, l15 = lane & 15, l4 = lane >> 4;
  const int wm = w >> 1, wn = w & 1;
  f32x4 acc[4][4] = {};
  const size_t strA = (size_t)Kk * 2;          // bytes per row
  const char* Abase = (const char*)A + (size_t)bm * strA;
  const char* Wbase = (const char*)W + (size_t)bn * strA;
  const size_t soff = (size_t)(tid >> 2) * strA + (size_t)((tid & 3) * 16);
  const int ldsOff = w * 1024;

#define STAGEK(K0, BUF) do { \
    const char* a0_ = Abase + soff + (size_t)(K0)*2; \
    const char* b0_ = Wbase + soff + (size_t)(K0)*2; \
    char* la_ = (char*)As + (BUF)*8192 + ldsOff; \
    char* lb_ = (char*)Bs + (BUF)*8192 + ldsOff; \
    gload16(a0_,            la_); \
    gload16(a0_ + 64*strA,  la_ + 4096); \
    gload16(b0_,            lb_); \
    gload16(b0_ + 64*strA,  lb_ + 4096); \
  } while(0)

  STAGEK(0, 0);
  const int nk = Kk >> 5;
  for (int t = 0; t < nk; t++) {
    __syncthreads();                       // buf[t&1] staged; prior reads done
    if (t + 1 < nk) STAGEK((t+1)*32, (t+1)&1);   // prefetch under this tile's MFMAs
    const short* AsC = (const short*)As + (t&1)*4096;
    const short* BsC = (const short*)Bs + (t&1)*4096;
    bf16x8 af[4], bfr[4];
    #pragma unroll
    for (int mf = 0; mf < 4; mf++)
      af[mf] = *(const bf16x8*)(AsC + (wm*64 + mf*16 + l15)*32 + l4*8);
    #pragma unroll
    for (int nf = 0; nf < 4; nf++)
      bfr[nf] = *(const bf16x8*)(BsC + (wn*64 + nf*16 + l15)*32 + l4*8);
    #pragma unroll
    for (int mf = 0; mf < 4; mf++)
      #pragma unroll
      for (int nf = 0; nf < 4; nf++)
        acc[mf][nf] = MFMA16(af[mf], bfr[nf], acc[mf][nf]);
  }
#undef STAGEK

  #pragma unroll
  for (int mf = 0; mf < 4; mf++) {
    #pragma unroll
    for (int nf = 0; nf < 4; nf++) {
      const int ccol = bn + wn*64 + nf*16 + l15;
      const float bv = bias[ccol];
      #pragma unroll
      for (int r = 0; r < 4; r++) {
        const int rrow = bm + wm*64 + mf*16 + l4*4 + r;
        float o = acc[mf][nf][r] + bv;
        if (RELU) o = fmaxf(o, 0.f);
        if (RES)  o += Rsd[(size_t)rrow*Nn + ccol];
        if (BOUT == 1)      Cb[(size_t)rrow*Nn + ccol] = f2b(o);
        else if (BOUT == 0) Cf[(size_t)rrow*Nn + ccol] = o;
        else { Cf[(size_t)rrow*Nn + ccol] = o; Cb[(size_t)rrow*Nn + ccol] = f2b(o); }
      }
    }
  }
}

// ---------------- MFMA flash attention ---------------------------------------------
// block = (b,h, 64-q-tile); 4 waves x 16 q-rows. K-tiles of 64 over keys 0..1023.
// defer-max (THR=8) + l-via-MFMA(ones) + setprio around MFMA clusters.
__global__ __launch_bounds__(256) void mattn_kernel(
    const unsigned short* __restrict__ QKV, unsigned short* __restrict__ Ctx)
{
  __shared__ short Ks[64*72];      // [key][hd], 144B row stride
  __shared__ short Vt[64*72];      // [hd][key] transposed, slot-XOR swizzled
  __shared__ short Ps[4*16*72];    // per-wave P tile [q][key]
  const int bid = blockIdx.x;
  const int qt = bid % QT_;
  const int h  = (bid / QT_) % H_;
  const int bb = bid / (QT_*H_);
  const int tid = threadIdx.x;
  const int w = tid >> 6, lane = tid & 63, l15 = lane & 15, l4 = lane >> 4;

  const size_t rowQ = (size_t)bb*S_ + (size_t)qt*64 + w*16 + l15;
  const unsigned short* qp = QKV + rowQ*1536 + h*64;
  const bf16x8 qf0 = *(const bf16x8*)(qp + l4*8);
  const bf16x8 qf1 = *(const bf16x8*)(qp + 32 + l4*8);

  const unsigned short* Kg = QKV + (size_t)bb*S_*1536 + 512 + h*64;
  const unsigned short* Vg = Kg + 512;

  f32x4 ctx[4] = {};
  f32x4 lacc = {};                 // row-sum accumulator (all cols identical)
  float m_r[4];
  #pragma unroll
  for (int r = 0; r < 4; r++) m_r[r] = -3.0e38f;

  const bf16x8 onesv = {(short)0x3F80,(short)0x3F80,(short)0x3F80,(short)0x3F80,
                        (short)0x3F80,(short)0x3F80,(short)0x3F80,(short)0x3F80};

  char* PsW = (char*)Ps + w*2304;            // 16*144 bytes per wave

  const int skey = tid >> 3, shc = tid & 7;  // K staging: key row, 16B hd-chunk
  const int vp   = tid >> 3, vhc = tid & 7;  // V staging: key pair, 16B hd-chunk

  for (int kt = 0; kt < 16; kt++) {
    __syncthreads();
    { // stage K tile [64][64] bf16 (2 rounds of 32 keys)
      const unsigned short* g0 = Kg + (size_t)(kt*64 + skey)*1536 + shc*8;
      bf16x8 k0v = *(const bf16x8*)g0;
      bf16x8 k1v = *(const bf16x8*)(g0 + 32*1536);
      *(bf16x8*)((char*)Ks + skey*144      + shc*16) = k0v;
      *(bf16x8*)((char*)Ks + (skey+32)*144 + shc*16) = k1v;
    }
    { // stage V transposed: Vt[hd][key], element key k at slot ((k>>3)^hc)
      const unsigned short* g0 = Vg + (size_t)(kt*64 + 2*vp)*1536 + vhc*8;
      bf16x8 c0 = *(const bf16x8*)g0;
      bf16x8 c1 = *(const bf16x8*)(g0 + 1536);
      #pragma unroll
      for (int j = 0; j < 8; j++) {
        const int hd = vhc*8 + j;
        unsigned int val = (unsigned int)(unsigned short)c0[j]
                         | ((unsigned int)(unsigned short)c1[j] << 16);
        *(unsigned int*)((char*)Vt + hd*144 + ((4*vp) ^ (vhc<<4))) = val;
      }
    }
    __syncthreads();

    // S = Q K^T  (scores for 16 q-rows x 64 keys per wave)
    f32x4 sac[4] = {};
    __builtin_amdgcn_s_setprio(1);
    #pragma unroll
    for (int nf = 0; nf < 4; nf++) {
      const char* kb = (char*)Ks + (nf*16 + l15)*144 + l4*16;
      bf16x8 b0 = *(const bf16x8*)kb;
      bf16x8 b1 = *(const bf16x8*)(kb + 64);
      sac[nf] = MFMA16(qf0, b0, sac[nf]);
      sac[nf] = MFMA16(qf1, b1, sac[nf]);
    }
    __builtin_amdgcn_s_setprio(0);

    // scale + lane-local max
    float sv[4][4], lmax[4];
    #pragma unroll
    for (int r = 0; r < 4; r++) lmax[r] = -3.0e38f;
    #pragma unroll
    for (int nf = 0; nf < 4; nf++)
      #pragma unroll
      for (int r = 0; r < 4; r++) {
        float v = sac[nf][r]*0.125f;
        sv[nf][r] = v;
        lmax[r] = fmaxf(lmax[r], v);
      }
    // defer-max: skip reduce+rescale when no row grew past m+8 (wave-uniform)
    int ok = 1;
    #pragma unroll
    for (int r = 0; r < 4; r++) ok &= (lmax[r] <= m_r[r] + 8.f) ? 1 : 0;
    if (!__all(ok)) {
      #pragma unroll
      for (int r = 0; r < 4; r++) {
        float t = lmax[r];
        t = fmaxf(t, __shfl_xor(t, 1, 64));
        t = fmaxf(t, __shfl_xor(t, 2, 64));
        t = fmaxf(t, __shfl_xor(t, 4, 64));
        t = fmaxf(t, __shfl_xor(t, 8, 64));
        const float mn = fmaxf(m_r[r], t);
        const float scl = __expf(m_r[r] - mn);
        m_r[r] = mn;
        lacc[r] *= scl;
        ctx[0][r] *= scl; ctx[1][r] *= scl;
        ctx[2][r] *= scl; ctx[3][r] *= scl;
      }
    }
    // P = exp(s - m) -> LDS bf16
    #pragma unroll
    for (int r = 0; r < 4; r++) {
      unsigned short* pw = (unsigned short*)(PsW + (l4*4 + r)*144);
      pw[ 0 + l15] = f2b(__expf(sv[0][r] - m_r[r]));
      pw[16 + l15] = f2b(__expf(sv[1][r] - m_r[r]));
      pw[32 + l15] = f2b(__expf(sv[2][r] - m_r[r]));
      pw[48 + l15] = f2b(__expf(sv[3][r] - m_r[r]));
    }

    // PV: ctx += P(16xkeys) * V(keys x 64hd); l += P * ones
    const char* pb = PsW + l15*144 + l4*16;
    const bf16x8 pf0 = *(const bf16x8*)pb;
    const bf16x8 pf1 = *(const bf16x8*)(pb + 64);
    __builtin_amdgcn_s_setprio(1);
    lacc = MFMA16(pf0, onesv, lacc);
    lacc = MFMA16(pf1, onesv, lacc);
    #pragma unroll
    for (int hf = 0; hf < 4; hf++) {
      const int hd = hf*16 + l15;
      const int hc = (hd >> 3) & 7;
      const char* vb = (char*)Vt + hd*144;
      bf16x8 v0 = *(const bf16x8*)(vb + ((l4*16)     ^ (hc<<4)));
      bf16x8 v1 = *(const bf16x8*)(vb + (((l4+4)*16) ^ (hc<<4)));
      ctx[hf] = MFMA16(pf0, v0, ctx[hf]);
      ctx[hf] = MFMA16(pf1, v1, ctx[hf]);
    }
    __builtin_amdgcn_s_setprio(0);
  }

  // epilogue: divide by l, store bf16 ctx
  #pragma unroll
  for (int r = 0; r < 4; r++) {
    const float invl = 1.0f / lacc[r];
    const size_t row = (size_t)bb*S_ + (size_t)qt*64 + w*16 + l4*4 + r;
    unsigned short* op = Ctx + row*512 + h*64;
    op[ 0 + l15] = f2b(ctx[0][r]*invl);
    op[16 + l15] = f2b(ctx[1][r]*invl);
    op[32 + l15] = f2b(ctx[2][r]*invl);
    op[48 + l15] = f2b(ctx[3][r]*invl);
  }
}

// ---------------- row LayerNorm over D=512, dual fp32/bf16 out ---------------------
__global__ __launch_bounds__(256) void ln_kernel(
    const float* __restrict__ Yin, const float* __restrict__ g, const float* __restrict__ b,
    float* __restrict__ Xf, unsigned short* __restrict__ Xb)
{
  int row = blockIdx.x, tid = threadIdx.x;
  const float* yr = Yin + (size_t)row*D_;
  float v0 = yr[tid], v1 = yr[tid + 256];
  __shared__ float red[4];
  float s = waveSum(v0 + v1);
  if ((tid & 63) == 0) red[tid >> 6] = s;
  __syncthreads();
  float mu = (red[0] + red[1] + red[2] + red[3]) * (1.f/512.f);
  __syncthreads();
  float d0 = v0 - mu, d1 = v1 - mu;
  float ss = waveSum(d0*d0 + d1*d1);
  if ((tid & 63) == 0) red[tid >> 6] = ss;
  __syncthreads();
  float inv = rsqrtf((red[0] + red[1] + red[2] + red[3]) * (1.f/512.f) + 1e-5f);
  float o0 = d0 * inv * g[tid]       + b[tid];
  float o1 = d1 * inv * g[tid + 256] + b[tid + 256];
  Xf[(size_t)row*D_ + tid]       = o0;
  Xf[(size_t)row*D_ + tid + 256] = o1;
  Xb[(size_t)row*D_ + tid]       = f2b(o0);
  Xb[(size_t)row*D_ + tid + 256] = f2b(o1);
}

// ---------------- head: X[:, -Q:] @ W_head[512,32] + b_head ------------------------
__global__ __launch_bounds__(64) void head_kernel(
    const float* __restrict__ X, const float* __restrict__ W_head,
    const float* __restrict__ b_head, float* __restrict__ out)
{
  int row = blockIdx.x;            // 0..B_*Q_-1
  int bb = row / Q_, qi = row % Q_;
  const float* xr = X + (size_t)(bb*S_ + C_ + qi)*D_;
  __shared__ float xs[512];
  int tid = threadIdx.x;
  for (int i = tid; i < 512; i += 64) xs[i] = xr[i];
  __syncthreads();
  if (tid < 32) {
    float acc = b_head[tid];
    #pragma unroll 8
    for (int k = 0; k < 512; k++) acc += xs[k] * W_head[k*32 + tid];
    out[(size_t)row*32 + tid] = acc;
  }
}

extern "C" void kernel_launch(void* const* d_in, const int* in_sizes, int n_in,
                              void* d_out, int out_size, void* d_ws, size_t ws_size,
                              hipStream_t stream)
{
  const float* x_c      = (const float*)d_in[0];
  const float* y_c      = (const float*)d_in[1];
  const float* x_q      = (const float*)d_in[2];
  const float* W_val    = (const float*)d_in[3];
  const float* b_val    = (const float*)d_in[4];
  const float* q_emb    = (const float*)d_in[5];
  const float* in_proj_w= (const float*)d_in[6];
  const float* in_proj_b= (const float*)d_in[7];
  const float* out_w    = (const float*)d_in[8];
  const float* out_b    = (const float*)d_in[9];
  const float* ln1_g    = (const float*)d_in[10];
  const float* ln1_b    = (const float*)d_in[11];
  const float* lin1_w   = (const float*)d_in[12];
  const float* lin1_b   = (const float*)d_in[13];
  const float* lin2_w   = (const float*)d_in[14];
  const float* lin2_b   = (const float*)d_in[15];
  const float* ln2_g    = (const float*)d_in[16];
  const float* ln2_b    = (const float*)d_in[17];
  const float* W_head   = (const float*)d_in[18];
  const float* b_head   = (const float*)d_in[19];
  float* out = (float*)d_out;

  // workspace layout (~250 MB)
  char* p = (char*)d_ws;
  float* X = (float*)p;                 p += (size_t)M_*D_*4;       // fp32 residual stream
  char*  YH = p;                        p += (size_t)M_*HID_*2;     // Y fp32 / hid bf16 (alias)
  float* Y = (float*)YH;
  unsigned short* hid = (unsigned short*)YH;
  unsigned short* Xb   = (unsigned short*)p; p += (size_t)M_*D_*2;
  unsigned short* qkv  = (unsigned short*)p; p += (size_t)M_*3*D_*2;
  unsigned short* ctxb = (unsigned short*)p; p += (size_t)M_*D_*2;
  unsigned short* ipwB = (unsigned short*)p; p += (size_t)L_*3*D_*D_*2;
  unsigned short* owB  = (unsigned short*)p; p += (size_t)L_*D_*D_*2;
  unsigned short* w1B  = (unsigned short*)p; p += (size_t)L_*HID_*D_*2;
  unsigned short* w2B  = (unsigned short*)p; p += (size_t)L_*D_*HID_*2;
  unsigned short* XYb  = (unsigned short*)p; p += (size_t)M_*128*2;
  unsigned short* Wemb = (unsigned short*)p; p += (size_t)D_*128*2;
  float* zbias         = (float*)p;          p += 2048*4;

  hipMemsetAsync(zbias, 0, 2048*4, stream);

  // convert weights to bf16
  f2b_kernel<<<512, 256, 0, stream>>>(in_proj_w, ipwB, L_*3*D_*D_/4);
  f2b_kernel<<<512, 256, 0, stream>>>(out_w,     owB,  L_*D_*D_/4);
  f2b_kernel<<<512, 256, 0, stream>>>(lin1_w,    w1B,  L_*HID_*D_/4);
  f2b_kernel<<<512, 256, 0, stream>>>(lin2_w,    w2B,  L_*D_*HID_/4);
  wemb_kernel<<<256, 256, 0, stream>>>(W_val, b_val, q_emb, Wemb);
  packxy_kernel<<<1024, 256, 0, stream>>>(x_c, y_c, x_q, XYb);

  // embedding as GEMM (dual fp32+bf16 out)
  bgemm_kernel<0,0,2><<<dim3(4, 144), 256, 0, stream>>>(
      XYb, Wemb, zbias, nullptr, X, Xb, D_, 128);

  for (int l = 0; l < L_; l++) {
    // QKV projection (bf16 out)
    bgemm_kernel<0,0,1><<<dim3(12, 144), 256, 0, stream>>>(
        Xb, ipwB + (size_t)l*3*D_*D_, in_proj_b + (size_t)l*3*D_,
        nullptr, nullptr, qkv, 3*D_, D_);
    // attention
    mattn_kernel<<<B_*H_*QT_, 256, 0, stream>>>(qkv, ctxb);
    // out-proj + residual(X) -> Y fp32
    bgemm_kernel<0,1,0><<<dim3(4, 144), 256, 0, stream>>>(
        ctxb, owB + (size_t)l*D_*D_, out_b + (size_t)l*D_,
        X, Y, nullptr, D_, D_);
    ln_kernel<<<M_, 256, 0, stream>>>(Y, ln1_g + (size_t)l*D_, ln1_b + (size_t)l*D_, X, Xb);
    // FFN1 (relu, bf16 out)
    bgemm_kernel<1,0,1><<<dim3(16, 144), 256, 0, stream>>>(
        Xb, w1B + (size_t)l*HID_*D_, lin1_b + (size_t)l*HID_,
        nullptr, nullptr, hid, HID_, D_);
    // FFN2 + residual(X) -> X (in-place)
    bgemm_kernel<0,1,0><<<dim3(4, 144), 256, 0, stream>>>(
        hid, w2B + (size_t)l*D_*HID_, lin2_b + (size_t)l*D_,
        X, X, nullptr, D_, HID_);
    ln_kernel<<<M_, 256, 0, stream>>>(X, ln2_g + (size_t)l*D_, ln2_b + (size_t)l*D_, X, Xb);
  }

  head_kernel<<<B_*Q_, 64, 0, stream>>>(X, W_head, b_head, out);
}